// Round 4
// baseline (276.257 us; speedup 1.0000x reference)
//
#include <hip/hip_runtime.h>
#include <hip/hip_fp16.h>

#define DIM 64
#define SLOPE 0.01f
#define NB 64   // nodes per block in node_proj

// ---------------------------------------------------------------------------
// Kernel 1: per-node projections.
// Block = 256 threads = 4 waves, NB=64 nodes. v tile in LDS; lane k holds
// Wa/Wg row k in registers. Outputs: packed fp16 table zu (x=z_k, y=u_k)
// and per-node fp32 scalars s_l = z.a_l, s_r = z.a_r, t = v.gr, g0 = v.gl.
// ---------------------------------------------------------------------------
__global__ __launch_bounds__(256) void node_proj(
    const float* __restrict__ v, const float* __restrict__ Wa,
    const float* __restrict__ Wg, const float* __restrict__ a_l,
    const float* __restrict__ a_r, const float* __restrict__ gl,
    const float* __restrict__ gr,
    __half2* __restrict__ zu,
    float* __restrict__ s_l, float* __restrict__ s_r,
    float* __restrict__ t_gr, float* __restrict__ g0, int N)
{
    __shared__ float vt[NB * DIM];            // 16 KB
    int tid = threadIdx.x;
    int base = blockIdx.x * NB;
    int nvalid = N - base; if (nvalid > NB) nvalid = NB;

    const float4* vsrc = (const float4*)(v + (size_t)base * DIM);
    float4* vdst = (float4*)vt;
    for (int i = tid; i < NB * DIM / 4; i += 256) {
        int row = i >> 4;                     // 16 float4 per row
        float4 q = make_float4(0.f, 0.f, 0.f, 0.f);
        if (row < nvalid) q = vsrc[i];
        vdst[i] = q;
    }
    __syncthreads();

    int k = tid & 63, g = tid >> 6;
    float wa[DIM], wg[DIM];
    const float4* wap = (const float4*)(Wa + k * DIM);
    const float4* wgp = (const float4*)(Wg + k * DIM);
#pragma unroll
    for (int i = 0; i < 16; i++) {
        float4 qa = wap[i], qg = wgp[i];
        wa[4*i+0]=qa.x; wa[4*i+1]=qa.y; wa[4*i+2]=qa.z; wa[4*i+3]=qa.w;
        wg[4*i+0]=qg.x; wg[4*i+1]=qg.y; wg[4*i+2]=qg.z; wg[4*i+3]=qg.w;
    }
    float alk = a_l[k], ark = a_r[k], grk = gr[k], glk = gl[k];

    for (int j = 0; j < NB / 4; j++) {
        int nl = g * (NB / 4) + j;
        int n = base + nl;
        if (n >= N) break;
        const float4* vrow = (const float4*)(vt + nl * DIM);
        float zk = 0.f, uk = 0.f;
#pragma unroll
        for (int i4 = 0; i4 < 16; i4++) {
            float4 q = vrow[i4];              // wave-broadcast LDS read
            zk += q.x * wa[4*i4+0] + q.y * wa[4*i4+1] + q.z * wa[4*i4+2] + q.w * wa[4*i4+3];
            uk += q.x * wg[4*i4+0] + q.y * wg[4*i4+1] + q.z * wg[4*i4+2] + q.w * wg[4*i4+3];
        }
        zu[(size_t)n * DIM + k] = __floats2half2_rn(zk, uk);  // 256B coalesced
        float vk = vt[nl * DIM + k];
        float r1 = zk * alk, r2 = zk * ark, r3 = vk * grk, r4 = vk * glk;
        for (int off = 32; off; off >>= 1) {
            r1 += __shfl_down(r1, off, 64);
            r2 += __shfl_down(r2, off, 64);
            r3 += __shfl_down(r3, off, 64);
            r4 += __shfl_down(r4, off, 64);
        }
        if (k == 0) { s_l[n] = r1; s_r[n] = r2; t_gr[n] = r3; g0[n] = r4; }
    }
}

// ---------------------------------------------------------------------------
// CSR build: count -> scan (3 small kernels) -> scatter
// ---------------------------------------------------------------------------
__global__ __launch_bounds__(256) void count_edges(
    const int* __restrict__ dst, int* __restrict__ cnt, int E)
{
    int i = blockIdx.x * 256 + threadIdx.x;
    int e = i * 4;
    if (e + 3 < E) {
        int4 d = *(const int4*)(dst + e);
        atomicAdd(&cnt[d.x], 1); atomicAdd(&cnt[d.y], 1);
        atomicAdd(&cnt[d.z], 1); atomicAdd(&cnt[d.w], 1);
    } else {
        for (; e < E; e++) atomicAdd(&cnt[dst[e]], 1);
    }
}

__global__ __launch_bounds__(256) void scan_reduce(
    const int* __restrict__ cnt, int* __restrict__ bsum, int N)
{
    __shared__ int lds[256];
    int base = blockIdx.x * 1024;
    int s = 0;
    for (int i = threadIdx.x; i < 1024; i += 256) {
        int idx = base + i;
        if (idx < N) s += cnt[idx];
    }
    lds[threadIdx.x] = s;
    __syncthreads();
    for (int off = 128; off; off >>= 1) {
        if (threadIdx.x < off) lds[threadIdx.x] += lds[threadIdx.x + off];
        __syncthreads();
    }
    if (threadIdx.x == 0) bsum[blockIdx.x] = lds[0];
}

__global__ void scan_bsum(int* __restrict__ bsum, int nb)
{
    int i = threadIdx.x;
    int x = (i < nb) ? bsum[i] : 0;
    int incl = x;
    for (int off = 1; off < 64; off <<= 1) {
        int y = __shfl_up(incl, off, 64);
        if (i >= off) incl += y;
    }
    if (i < nb) bsum[i] = incl - x;
}

__global__ __launch_bounds__(256) void scan_final(
    const int* __restrict__ cnt, const int* __restrict__ bsum,
    int* __restrict__ offs, int* __restrict__ cursor, int N)
{
    __shared__ int lds[256];
    int base = blockIdx.x * 1024;
    int t = threadIdx.x;
    int idx0 = base + t * 4;
    int v4[4];
    int s = 0;
#pragma unroll
    for (int j = 0; j < 4; j++) {
        int idx = idx0 + j;
        int c = (idx < N) ? cnt[idx] : 0;
        v4[j] = s;
        s += c;
    }
    lds[t] = s;
    __syncthreads();
    for (int off = 1; off < 256; off <<= 1) {
        int y = (t >= off) ? lds[t - off] : 0;
        __syncthreads();
        lds[t] += y;
        __syncthreads();
    }
    int excl = lds[t] - s + bsum[blockIdx.x];
#pragma unroll
    for (int j = 0; j < 4; j++) {
        int idx = idx0 + j;
        if (idx < N) {
            int o = excl + v4[j];
            offs[idx] = o;
            cursor[idx] = o;
        }
    }
}

// scatter edges into CSR order. ONE 8B store per edge ({src, pw} packed);
// the edge score is recomputed later in edge_softmax, halving the random
// scattered line-touches vs writing a separate score array.
__global__ __launch_bounds__(256) void scatter_edges(
    const int* __restrict__ src, const int* __restrict__ dst,
    const float* __restrict__ pre_w,
    int* __restrict__ cursor,
    int2* __restrict__ sp_s, int E)
{
    int e = blockIdx.x * 256 + threadIdx.x;
    if (e >= E) return;
    int s = src[e], d = dst[e];
    float pw = pre_w[e];
    int pos = atomicAdd(&cursor[d], 1);
    int2 sp; sp.x = s; sp.y = __float_as_int(pw);
    sp_s[pos] = sp;
}

// ---------------------------------------------------------------------------
// Per-dst softmax: recompute ea = leaky(pw*s_l[src] + s_r[n]) inline
// (s_r[n] segment-uniform, s_l gather is a 200KB L2-hot table), then
// max / exp-sum / normalize. Writes alpha contiguously per segment.
// 16-lane subgroup per node (deg avg 16).
// ---------------------------------------------------------------------------
__global__ __launch_bounds__(256) void edge_softmax(
    const int* __restrict__ offs, const int* __restrict__ cnt,
    const int2* __restrict__ sp_s,
    const float* __restrict__ s_l, const float* __restrict__ s_r,
    float* __restrict__ alpha_s, int N)
{
    int n = (blockIdx.x * 256 + threadIdx.x) >> 4;
    int lane = threadIdx.x & 15;
    if (n >= N) return;
    int deg = cnt[n];
    if (deg == 0) return;
    int start = offs[n];
    float srn = s_r[n];
    float m = -INFINITY;
    for (int j = lane; j < deg; j += 16) {
        int2 sp = sp_s[start + j];
        float pw = __int_as_float(sp.y);
        float ea = fmaf(pw, s_l[sp.x], srn);
        ea = ea > 0.f ? ea : SLOPE * ea;      // leaky_relu
        alpha_s[start + j] = ea;              // contiguous per segment
        m = fmaxf(m, ea);
    }
#pragma unroll
    for (int mask = 8; mask; mask >>= 1) m = fmaxf(m, __shfl_xor(m, mask, 64));
    float ssum = 0.f;
    for (int j = lane; j < deg; j += 16) {
        float ex = __expf(alpha_s[start + j] - m);   // L1-hot reread
        alpha_s[start + j] = ex;
        ssum += ex;
    }
#pragma unroll
    for (int mask = 8; mask; mask >>= 1) ssum += __shfl_xor(ssum, mask, 64);
    float inv = 1.f / fmaxf(ssum, 1e-16f);
    for (int j = lane; j < deg; j += 16) alpha_s[start + j] *= inv;
}

// ---------------------------------------------------------------------------
// Aggregate: one wave per dst node, lane = feature dim. One packed 4B/lane
// gather per edge (fp16 z|u). Unrolled x8 (deg avg 16 -> 2 iterations) so
// 8 independent gathers are in flight. Metadata via the scalar pipe.
// ---------------------------------------------------------------------------
__global__ __launch_bounds__(256) void aggregate(
    const int* __restrict__ offs, const int* __restrict__ cnt,
    const int2* __restrict__ sp_s, const float* __restrict__ alpha_s,
    const __half2* __restrict__ zu,
    const float* __restrict__ t_gr, const float* __restrict__ g0,
    const float* __restrict__ gm,
    float* __restrict__ out, int N)
{
    int n = __builtin_amdgcn_readfirstlane((blockIdx.x * 256 + threadIdx.x) >> 6);
    int k = threadIdx.x & 63;
    if (n >= N) return;
    int deg = cnt[n];
    size_t outIdx = (size_t)n * DIM + k;
    if (deg == 0) { out[outIdx] = 0.f; return; }
    int start = offs[n];

    float hk = 0.f, mfk = -INFINITY, msum = 0.f;
    int j = 0;
    for (; j + 8 <= deg; j += 8) {
        int p = start + j;
        int2 sp[8]; float al[8]; __half2 q[8]; float ts[8];
#pragma unroll
        for (int i = 0; i < 8; i++) sp[i] = sp_s[p + i];      // scalar seq
#pragma unroll
        for (int i = 0; i < 8; i++) al[i] = alpha_s[p + i];   // scalar seq
#pragma unroll
        for (int i = 0; i < 8; i++) q[i] = zu[(size_t)sp[i].x * DIM + k];
#pragma unroll
        for (int i = 0; i < 8; i++) ts[i] = t_gr[sp[i].x];    // scalar
#pragma unroll
        for (int i = 0; i < 8; i++) {
            float2 f = __half22float2(q[i]);
            float pw = __int_as_float(sp[i].y);
            hk = fmaf(al[i], f.x, hk);
            mfk = fmaxf(mfk, pw * f.y);
            msum = fmaf(pw, ts[i], msum);
        }
    }
    for (; j + 4 <= deg; j += 4) {
        int p = start + j;
        int2 sp[4]; float al[4]; __half2 q[4]; float ts[4];
#pragma unroll
        for (int i = 0; i < 4; i++) sp[i] = sp_s[p + i];
#pragma unroll
        for (int i = 0; i < 4; i++) al[i] = alpha_s[p + i];
#pragma unroll
        for (int i = 0; i < 4; i++) q[i] = zu[(size_t)sp[i].x * DIM + k];
#pragma unroll
        for (int i = 0; i < 4; i++) ts[i] = t_gr[sp[i].x];
#pragma unroll
        for (int i = 0; i < 4; i++) {
            float2 f = __half22float2(q[i]);
            float pw = __int_as_float(sp[i].y);
            hk = fmaf(al[i], f.x, hk);
            mfk = fmaxf(mfk, pw * f.y);
            msum = fmaf(pw, ts[i], msum);
        }
    }
    for (; j < deg; j++) {
        int p = start + j;
        int2 sp = sp_s[p];
        float al = alpha_s[p];
        __half2 q = zu[(size_t)sp.x * DIM + k];
        float pw = __int_as_float(sp.y);
        float2 f = __half22float2(q);
        hk = fmaf(al, f.x, hk);
        mfk = fmaxf(mfk, pw * f.y);
        msum = fmaf(pw, t_gr[sp.x], msum);
    }
    // wave reduction: maxFeat . gm
    float r = gm[k] * mfk;
    for (int off = 32; off; off >>= 1) r += __shfl_down(r, off, 64);
    r = __shfl(r, 0, 64);
    float meanDot = msum / (float)deg;
    float x = g0[n] + r + meanDot;
    float gate = 1.f / (1.f + __expf(-x));
    out[outIdx] = gate * hk;
}

// ---------------------------------------------------------------------------
extern "C" void kernel_launch(void* const* d_in, const int* in_sizes, int n_in,
                              void* d_out, int out_size, void* d_ws, size_t ws_size,
                              hipStream_t stream)
{
    const float* v     = (const float*)d_in[0];
    const float* pre_w = (const float*)d_in[1];
    const int*   src   = (const int*)d_in[2];
    const int*   dst   = (const int*)d_in[3];
    const float* Wa    = (const float*)d_in[4];
    const float* a_l   = (const float*)d_in[5];
    const float* a_r   = (const float*)d_in[6];
    const float* Wg    = (const float*)d_in[7];
    const float* gl    = (const float*)d_in[8];
    const float* gm    = (const float*)d_in[9];
    const float* gr    = (const float*)d_in[10];
    int N = in_sizes[0] / DIM;
    int E = in_sizes[2];

    // workspace layout (~24 MB)
    char* ws   = (char*)d_ws;
    __half2* zu = (__half2*)ws;                       // N*DIM*4B = 12.8MB
    float* s_l  = (float*)(ws + (size_t)N * DIM * 4);
    float* s_r  = s_l + N;
    float* t_gr = s_r + N;
    float* g0   = t_gr + N;
    int* cnt    = (int*)(g0 + N);
    int* offs   = cnt + N;
    int* cursor = offs + N;
    int* bsum   = cursor + N;
    int nb = (N + 1023) / 1024;
    int2* sp_s  = (int2*)(bsum + ((nb + 63) / 64) * 64);
    float* alpha_s = (float*)(sp_s + E);

    hipMemsetAsync(cnt, 0, (size_t)N * sizeof(int), stream);

    node_proj<<<(N + NB - 1) / NB, 256, 0, stream>>>(
        v, Wa, Wg, a_l, a_r, gl, gr, zu, s_l, s_r, t_gr, g0, N);

    count_edges<<<(E / 4 + 255) / 256, 256, 0, stream>>>(dst, cnt, E);
    scan_reduce<<<nb, 256, 0, stream>>>(cnt, bsum, N);
    scan_bsum<<<1, 64, 0, stream>>>(bsum, nb);
    scan_final<<<nb, 256, 0, stream>>>(cnt, bsum, offs, cursor, N);

    scatter_edges<<<(E + 255) / 256, 256, 0, stream>>>(
        src, dst, pre_w, cursor, sp_s, E);

    edge_softmax<<<(N * 16 + 255) / 256, 256, 0, stream>>>(
        offs, cnt, sp_s, s_l, s_r, alpha_s, N);

    aggregate<<<(N + 3) / 4, 256, 0, stream>>>(
        offs, cnt, sp_s, alpha_s, zu, t_gr, g0, gm, (float*)d_out, N);
}